// Round 7
// baseline (6951.174 us; speedup 1.0000x reference)
//
#include <hip/hip_runtime.h>
#include <math.h>

#define B_ 16
#define S_ 256
#define T_ 256
#define E_ 1024
#define H_ 512
#define G_ 1536
#define V_ 32000

typedef unsigned short u16;
typedef short short8 __attribute__((ext_vector_type(8)));
typedef float f32x4 __attribute__((ext_vector_type(4)));

__device__ inline u16 f2bf(float x) {
  union { float f; unsigned u; } a; a.f = x;
  unsigned r = a.u + 0x7fff + ((a.u >> 16) & 1);
  return (u16)(r >> 16);
}
__device__ inline float bf2f(u16 h) {
  union { unsigned u; float f; } a; a.u = ((unsigned)h) << 16;
  return a.f;
}

// Coherent (MALL-level) 16B load: bypasses L1+L2, no cache maintenance.
// Caller MUST execute s_waitcnt vmcnt(0) before using the result.
__device__ inline f32x4 load_f4_coh(const float* p) {
  f32x4 v;
  asm volatile("global_load_dwordx4 %0, %1, off sc0 sc1" : "=v"(v) : "v"(p));
  return v;
}

__device__ inline float dot4(f32x4 a, f32x4 b) {
  return a.x * b.x + a.y * b.y + a.z * b.z + a.w * b.w;
}

// ---------------- embedding gathers ----------------
__global__ __launch_bounds__(256) void k_embed_enc(const int* __restrict__ sen,
                                                   const float* __restrict__ emb,
                                                   float* __restrict__ out) {
  long row = blockIdx.x;
  int tid = threadIdx.x;
  long e = sen[row];
  float4 v = *(const float4*)(emb + e * E_ + tid * 4);
  *(float4*)(out + row * E_ + tid * 4) = v;
}

__global__ __launch_bounds__(256) void k_embed_dec(const int* __restrict__ zh,
                                                   const float* __restrict__ emb,
                                                   float* __restrict__ out) {
  long row = blockIdx.x;
  int b = (int)(row >> 8), t = (int)(row & 255);
  int tid = threadIdx.x;
  long e = (t == 0) ? (V_ - 2) : zh[b * T_ + t - 1];
  float4 v = *(const float4*)(emb + e * E_ + tid * 4);
  *(float4*)(out + row * E_ + tid * 4) = v;
}

// ---------------- batched 32x32 tiled transpose ----------------
__global__ __launch_bounds__(256) void k_transpose(const float* __restrict__ in,
                                                   float* __restrict__ out, int R, int C) {
  __shared__ float tile[32][33];
  long z = blockIdx.z;
  const float* inz = in + z * (long)R * C;
  float* outz = out + z * (long)R * C;
  int x = blockIdx.x * 32 + threadIdx.x;
  int y0 = blockIdx.y * 32;
#pragma unroll
  for (int i = threadIdx.y; i < 32; i += 8)
    tile[i][threadIdx.x] = inz[(long)(y0 + i) * C + x];
  __syncthreads();
  int xo = y0 + threadIdx.x;
#pragma unroll
  for (int i = threadIdx.y; i < 32; i += 8) {
    int yo = blockIdx.x * 32 + i;
    outz[(long)yo * R + xo] = tile[threadIdx.x][i];
  }
}

// ---------------- fp32 SGEMM (small attention GEMMs) ----------------
__global__ __launch_bounds__(256) void k_gemm_nt(
    const float* __restrict__ A, int lda, const float* __restrict__ A2, int lda2, int kSplit,
    const float* __restrict__ Bm, int ldb, const float* __restrict__ bias,
    float* __restrict__ C, int ldc, int K, long sA, long sB, long sC) {
  __shared__ float As[8][132];
  __shared__ float Bs[8][132];
  int z = blockIdx.z;
  A += z * sA;
  Bm += z * sB;
  C += z * sC;
  int tid = threadIdx.x;
  int bm = blockIdx.y * 128, bn = blockIdx.x * 128;
  int tx = tid & 15, ty = tid >> 4;
  int lr = tid >> 1, lc = (tid & 1) * 4;
  float acc[8][8] = {};
  for (int k0 = 0; k0 < K; k0 += 8) {
    int ka = k0 + lc;
    const float* ap;
    if (A2 != nullptr && ka >= kSplit)
      ap = A2 + (long)(bm + lr) * lda2 + (ka - kSplit);
    else
      ap = A + (long)(bm + lr) * lda + ka;
    float4 a4 = *(const float4*)ap;
    float4 b4 = *(const float4*)(Bm + (long)(bn + lr) * ldb + k0 + lc);
    As[lc + 0][lr] = a4.x; As[lc + 1][lr] = a4.y; As[lc + 2][lr] = a4.z; As[lc + 3][lr] = a4.w;
    Bs[lc + 0][lr] = b4.x; Bs[lc + 1][lr] = b4.y; Bs[lc + 2][lr] = b4.z; Bs[lc + 3][lr] = b4.w;
    __syncthreads();
#pragma unroll
    for (int kk = 0; kk < 8; kk++) {
      float ar[8], br[8];
      *(float4*)&ar[0] = *(const float4*)&As[kk][ty * 8];
      *(float4*)&ar[4] = *(const float4*)&As[kk][ty * 8 + 4];
      *(float4*)&br[0] = *(const float4*)&Bs[kk][tx * 8];
      *(float4*)&br[4] = *(const float4*)&Bs[kk][tx * 8 + 4];
#pragma unroll
      for (int i = 0; i < 8; i++)
#pragma unroll
        for (int j = 0; j < 8; j++) acc[i][j] += ar[i] * br[j];
    }
    __syncthreads();
  }
  float bv[8];
#pragma unroll
  for (int j = 0; j < 8; j++) bv[j] = bias ? bias[bn + tx * 8 + j] : 0.f;
#pragma unroll
  for (int i = 0; i < 8; i++) {
    float* cp = C + (long)(bm + ty * 8 + i) * ldc + bn + tx * 8;
    float4 o0, o1;
    o0.x = acc[i][0] + bv[0]; o0.y = acc[i][1] + bv[1];
    o0.z = acc[i][2] + bv[2]; o0.w = acc[i][3] + bv[3];
    o1.x = acc[i][4] + bv[4]; o1.y = acc[i][5] + bv[5];
    o1.z = acc[i][6] + bv[6]; o1.w = acc[i][7] + bv[7];
    *(float4*)cp = o0;
    *(float4*)(cp + 4) = o1;
  }
}

// ---------------- split-bf16 MFMA GEMM (fp32 in/out) ----------------
__global__ __launch_bounds__(256) void k_gemm_mfma_nt(
    const float* __restrict__ A, int lda, const float* __restrict__ A2, int lda2, int kSplit,
    const float* __restrict__ Bm, int ldb, const float* __restrict__ bias,
    float* __restrict__ C, int ldc, int K) {
  __shared__ u16 Ah[128][40];
  __shared__ u16 Al[128][40];
  __shared__ u16 Bh[128][40];
  __shared__ u16 Bl[128][40];
  int tid = threadIdx.x;
  int bm = blockIdx.y * 128, bn = blockIdx.x * 128;
  int wave = tid >> 6, lane = tid & 63;
  int wm = (wave >> 1) * 64, wn = (wave & 1) * 64;
  int srow = tid >> 1, scol = (tid & 1) * 16;
  int fr = lane & 15, fk = (lane >> 4) * 8, fq = lane >> 4;

  f32x4 acc[4][4] = {};

  for (int k0 = 0; k0 < K; k0 += 32) {
    {
      int ka = k0 + scol;
      const float* ap;
      if (A2 != nullptr && ka >= kSplit)
        ap = A2 + (long)(bm + srow) * lda2 + (ka - kSplit);
      else
        ap = A + (long)(bm + srow) * lda + ka;
      float va[16];
      *(float4*)&va[0] = *(const float4*)ap;
      *(float4*)&va[4] = *(const float4*)(ap + 4);
      *(float4*)&va[8] = *(const float4*)(ap + 8);
      *(float4*)&va[12] = *(const float4*)(ap + 12);
      u16 h[16], l[16];
#pragma unroll
      for (int i = 0; i < 16; i++) {
        u16 hh = f2bf(va[i]);
        h[i] = hh;
        l[i] = f2bf(va[i] - bf2f(hh));
      }
      *(short8*)&Ah[srow][scol] = *(short8*)&h[0];
      *(short8*)&Ah[srow][scol + 8] = *(short8*)&h[8];
      *(short8*)&Al[srow][scol] = *(short8*)&l[0];
      *(short8*)&Al[srow][scol + 8] = *(short8*)&l[8];
    }
    {
      const float* bp = Bm + (long)(bn + srow) * ldb + k0 + scol;
      float vb[16];
      *(float4*)&vb[0] = *(const float4*)bp;
      *(float4*)&vb[4] = *(const float4*)(bp + 4);
      *(float4*)&vb[8] = *(const float4*)(bp + 8);
      *(float4*)&vb[12] = *(const float4*)(bp + 12);
      u16 h[16], l[16];
#pragma unroll
      for (int i = 0; i < 16; i++) {
        u16 hh = f2bf(vb[i]);
        h[i] = hh;
        l[i] = f2bf(vb[i] - bf2f(hh));
      }
      *(short8*)&Bh[srow][scol] = *(short8*)&h[0];
      *(short8*)&Bh[srow][scol + 8] = *(short8*)&h[8];
      *(short8*)&Bl[srow][scol] = *(short8*)&l[0];
      *(short8*)&Bl[srow][scol + 8] = *(short8*)&l[8];
    }
    __syncthreads();
    short8 afh[4], afl[4];
#pragma unroll
    for (int mt = 0; mt < 4; mt++) {
      afh[mt] = *(const short8*)&Ah[wm + mt * 16 + fr][fk];
      afl[mt] = *(const short8*)&Al[wm + mt * 16 + fr][fk];
    }
#pragma unroll
    for (int nt = 0; nt < 4; nt++) {
      short8 bh = *(const short8*)&Bh[wn + nt * 16 + fr][fk];
      short8 bl = *(const short8*)&Bl[wn + nt * 16 + fr][fk];
#pragma unroll
      for (int mt = 0; mt < 4; mt++) {
        acc[mt][nt] = __builtin_amdgcn_mfma_f32_16x16x32_bf16(afh[mt], bh, acc[mt][nt], 0, 0, 0);
        acc[mt][nt] = __builtin_amdgcn_mfma_f32_16x16x32_bf16(afh[mt], bl, acc[mt][nt], 0, 0, 0);
        acc[mt][nt] = __builtin_amdgcn_mfma_f32_16x16x32_bf16(afl[mt], bh, acc[mt][nt], 0, 0, 0);
      }
    }
    __syncthreads();
  }
#pragma unroll
  for (int nt = 0; nt < 4; nt++) {
    int col = bn + wn + nt * 16 + fr;
    float bv = bias ? bias[col] : 0.f;
#pragma unroll
    for (int mt = 0; mt < 4; mt++) {
      int row = bm + wm + mt * 16 + fq * 4;
#pragma unroll
      for (int j = 0; j < 4; j++)
        C[(long)(row + j) * ldc + col] = acc[mt][nt][j] + bv;
    }
  }
}

// ---------------- persistent GRU layer (v4: register weights + tight poll) ----------------
// grid = 128 blocks x 256 threads. wave = jj (j = bid*4 + wave).
// lane = bh*32 + ksl: bh = batch-half (0:b0-7, 1:b8-15), ksl = k-slice (16 k's).
// Weights: 48 floats/thread in VGPRs, loaded once. Per step only h read from LDS.
// hls layout (per batch row, stride 536): k -> q=(k>>2)&3, l=k>>4, i=k&3 at
// [q*132 + l*4 + i]  => ds_read_b128 at lane-stride 16B = conflict-free.
// Sync: wave 0 polls 128 per-block epoch slots (2/lane) with in-wave ballot;
// publish = vmcnt(0)-acked relaxed store of t+1. No L2 cache maintenance.
#define WSLOT 32
__global__ __launch_bounds__(256) void k_gru_layer(
    const float* __restrict__ xp, float* __restrict__ y,
    const float* __restrict__ Whh, const float* __restrict__ bhh,
    const float* __restrict__ hinit, long hbs, int* __restrict__ ep) {
  __shared__ float hls[16 * 536];
  int tid = threadIdx.x;
  int wave = tid >> 6, lane = tid & 63;
  int bh = lane >> 5, ksl = lane & 31;
  int j = blockIdx.x * 4 + wave;

  // ---- weights (3 gates x 16 k) + bias into registers, once ----
  f32x4 w[3][4];
  float bb0, bb1, bb2;
  {
    const float* r0 = Whh + (long)(0 * 512 + j) * 512 + ksl * 16;
    const float* r1 = Whh + (long)(1 * 512 + j) * 512 + ksl * 16;
    const float* r2 = Whh + (long)(2 * 512 + j) * 512 + ksl * 16;
#pragma unroll
    for (int q = 0; q < 4; q++) {
      w[0][q] = *(const f32x4*)(r0 + q * 4);
      w[1][q] = *(const f32x4*)(r1 + q * 4);
      w[2][q] = *(const f32x4*)(r2 + q * 4);
    }
    bb0 = bhh[j]; bb1 = bhh[j + 512]; bb2 = bhh[j + 1024];
  }
  bool gate_lane = (ksl < 8);
  int bg = bh * 8 + ksl;  // batch owned by this gate lane

  for (int t = 0; t < 256; t++) {
    // ---- xp prefetch (independent of recurrence) ----
    float xr = 0.f, xz = 0.f, xn = 0.f;
    if (gate_lane) {
      const float* xpt = xp + ((long)bg * 256 + t) * 1536 + j;
      xr = xpt[0]; xz = xpt[512]; xn = xpt[1024];
    }
    // ---- wait for peers: ep[*] >= t (wave 0 only) ----
    if (t > 0) {
      if (wave == 0) {
        while (true) {
          int e0, e1;
          asm volatile("global_load_dword %0, %1, off sc0 sc1"
                       : "=v"(e0) : "v"(ep + lane * WSLOT));
          asm volatile("global_load_dword %0, %1, off sc0 sc1"
                       : "=v"(e1) : "v"(ep + (lane + 64) * WSLOT));
          asm volatile("s_waitcnt vmcnt(0)" ::: "memory");
          bool ok = (e0 >= t) && (e1 >= t);
          if (__ballot(ok) == ~0ull) break;
          __builtin_amdgcn_s_sleep(1);
        }
      }
      __syncthreads();  // release all waves; also guards hls vs prev readers
    }
    // ---- stage h(t-1) [16][512] via coherent 16B loads, q-interleaved ----
    f32x4 hv4[8];
#pragma unroll
    for (int i = 0; i < 8; i++) {
      int f4 = i * 256 + tid;
      int b = f4 >> 7, k0 = (f4 & 127) * 4;
      const float* src = (t == 0) ? (hinit + (long)b * hbs + k0)
                                  : (y + ((long)b * 256 + (t - 1)) * 512 + k0);
      hv4[i] = load_f4_coh(src);
    }
    asm volatile("s_waitcnt vmcnt(0)" ::: "memory");
    __builtin_amdgcn_sched_barrier(0);
#pragma unroll
    for (int i = 0; i < 8; i++) {
      int f4 = i * 256 + tid;
      int b = f4 >> 7, k0 = (f4 & 127) * 4;
      *(f32x4*)&hls[b * 536 + ((k0 >> 2) & 3) * 132 + (k0 >> 4) * 4] = hv4[i];
    }
    __syncthreads();
    // ---- matvec: 8 batches (own half) x 3 gates x 16 k, weights in regs ----
    float a[8][3];
#pragma unroll
    for (int p = 0; p < 8; p++) { a[p][0] = 0.f; a[p][1] = 0.f; a[p][2] = 0.f; }
#pragma unroll
    for (int p = 0; p < 8; p++) {
      const float* hb = &hls[(bh * 8 + p) * 536 + ksl * 4];
      f32x4 h0 = *(const f32x4*)(hb);
      f32x4 h1 = *(const f32x4*)(hb + 132);
      f32x4 h2 = *(const f32x4*)(hb + 264);
      f32x4 h3 = *(const f32x4*)(hb + 396);
#pragma unroll
      for (int g = 0; g < 3; g++)
        a[p][g] = dot4(h0, w[g][0]) + dot4(h1, w[g][1]) +
                  dot4(h2, w[g][2]) + dot4(h3, w[g][3]);
    }
    // ---- reduce over the 32 k-slice lanes (masks 1..16 stay in-half) ----
#pragma unroll
    for (int m = 1; m <= 16; m <<= 1)
#pragma unroll
      for (int p = 0; p < 8; p++) {
        a[p][0] += __shfl_xor(a[p][0], m);
        a[p][1] += __shfl_xor(a[p][1], m);
        a[p][2] += __shfl_xor(a[p][2], m);
      }
    // ---- gates (lanes ksl<8; static-index select per rule #20) ----
    if (gate_lane) {
      float hr = 0.f, hz = 0.f, hn = 0.f;
#pragma unroll
      for (int p = 0; p < 8; p++)
        if (ksl == p) { hr = a[p][0]; hz = a[p][1]; hn = a[p][2]; }
      float r = 1.f / (1.f + __expf(-(xr + hr + bb0)));
      float z = 1.f / (1.f + __expf(-(xz + hz + bb1)));
      float n = tanhf(xn + r * (hn + bb2));
      float hp = hls[bg * 536 + ((j >> 2) & 3) * 132 + (j >> 4) * 4 + (j & 3)];
      float hv = (1.f - z) * n + z * hp;
      __hip_atomic_store(&y[((long)bg * 256 + t) * 512 + j], hv,
                         __ATOMIC_RELAXED, __HIP_MEMORY_SCOPE_AGENT);
    }
    // ---- publish: own stores acked at MALL, then epoch store ----
    asm volatile("s_waitcnt vmcnt(0)" ::: "memory");
    __syncthreads();  // all lanes' h stores acked; also ends hls read phase
    if (tid == 0)
      __hip_atomic_store(ep + blockIdx.x * WSLOT, t + 1,
                         __ATOMIC_RELAXED, __HIP_MEMORY_SCOPE_AGENT);
  }
}

// ---------------- row softmax over 256 ----------------
__global__ __launch_bounds__(256) void k_softmax(float* __restrict__ p) {
  long row = blockIdx.x;
  int tid = threadIdx.x;
  float* pr = p + row * 256;
  float v = pr[tid];
  float m = v;
#pragma unroll
  for (int off = 32; off >= 1; off >>= 1) m = fmaxf(m, __shfl_xor(m, off));
  __shared__ float wmax[4];
  __shared__ float wsum[4];
  int wv = tid >> 6, ln = tid & 63;
  if (ln == 0) wmax[wv] = m;
  __syncthreads();
  m = fmaxf(fmaxf(wmax[0], wmax[1]), fmaxf(wmax[2], wmax[3]));
  float e = expf(v - m);
  float s = e;
#pragma unroll
  for (int off = 32; off >= 1; off >>= 1) s += __shfl_xor(s, off);
  if (ln == 0) wsum[wv] = s;
  __syncthreads();
  s = wsum[0] + wsum[1] + wsum[2] + wsum[3];
  pr[tid] = e / s;
}

extern "C" void kernel_launch(void* const* d_in, const int* in_sizes, int n_in,
                              void* d_out, int out_size, void* d_ws, size_t ws_size,
                              hipStream_t stream) {
  const int* en_sen = (const int*)d_in[0];
  const int* zh_sen = (const int*)d_in[1];
  const float* en_emb = (const float*)d_in[2];
  const float* zh_emb = (const float*)d_in[3];
  const float* h0 = (const float*)d_in[4];
  const float* Wih_e0 = (const float*)d_in[5];
  const float* Whh_e0 = (const float*)d_in[6];
  const float* bih_e0 = (const float*)d_in[7];
  const float* bhh_e0 = (const float*)d_in[8];
  const float* Wih_e1 = (const float*)d_in[9];
  const float* Whh_e1 = (const float*)d_in[10];
  const float* bih_e1 = (const float*)d_in[11];
  const float* bhh_e1 = (const float*)d_in[12];
  const float* Wih_d0 = (const float*)d_in[13];
  const float* Whh_d0 = (const float*)d_in[14];
  const float* bih_d0 = (const float*)d_in[15];
  const float* bhh_d0 = (const float*)d_in[16];
  const float* Wih_d1 = (const float*)d_in[17];
  const float* Whh_d1 = (const float*)d_in[18];
  const float* bih_d1 = (const float*)d_in[19];
  const float* bhh_d1 = (const float*)d_in[20];
  const float* fcW = (const float*)d_in[21];
  const float* fcb = (const float*)d_in[22];
  float* out = (float*)d_out;

  // FC inputs must not alias d_out -> d_ws (16 MiB).
  float* decOut = (float*)d_ws;
  float* ctx = decOut + 2097152;

  // d_out scratch: epoch slots [4 layers][128 blocks][32 ints] = 64 KB, then buffers.
  int* flags = (int*)d_out;              // 16384 ints
  float* bufE = (float*)d_out + 16384;   // ex / zx  [B*256*1024]
  float* xp = bufE + 4194304;            // [B*256*1536]
  float* bufY = xp + 6291456;            // y_e0 then y_d0
  float* enOut = bufY + 2097152;         // y_e1
  float* scT = enOut + 2097152;          // scores/attn [B,T,S]
  float* enOutT = scT + 1048576;         // [B,512,256]

  hipMemsetAsync(flags, 0, 16384 * sizeof(int), stream);

  dim3 tb(32, 8);

  // ---------------- encoder ----------------
  k_embed_enc<<<B_ * S_, 256, 0, stream>>>(en_sen, en_emb, bufE);
  k_gemm_mfma_nt<<<dim3(G_ / 128, (B_ * S_) / 128, 1), 256, 0, stream>>>(
      bufE, E_, nullptr, 0, E_, Wih_e0, E_, bih_e0, xp, G_, E_);
  k_gru_layer<<<128, 256, 0, stream>>>(xp, bufY, Whh_e0, bhh_e0, h0, (long)H_, flags);
  k_gemm_mfma_nt<<<dim3(G_ / 128, (B_ * S_) / 128, 1), 256, 0, stream>>>(
      bufY, H_, nullptr, 0, H_, Wih_e1, H_, bih_e1, xp, G_, H_);
  k_gru_layer<<<128, 256, 0, stream>>>(xp, enOut, Whh_e1, bhh_e1, h0 + B_ * H_, (long)H_,
                                       flags + 4096);

  // ---------------- decoder ----------------
  k_embed_dec<<<B_ * T_, 256, 0, stream>>>(zh_sen, zh_emb, bufE);
  k_gemm_mfma_nt<<<dim3(G_ / 128, (B_ * T_) / 128, 1), 256, 0, stream>>>(
      bufE, E_, nullptr, 0, E_, Wih_d0, E_, bih_d0, xp, G_, E_);
  k_gru_layer<<<128, 256, 0, stream>>>(xp, bufY, Whh_d0, bhh_d0, bufY + 255 * H_,
                                       (long)(256 * H_), flags + 8192);
  k_gemm_mfma_nt<<<dim3(G_ / 128, (B_ * T_) / 128, 1), 256, 0, stream>>>(
      bufY, H_, nullptr, 0, H_, Wih_d1, H_, bih_d1, xp, G_, H_);
  k_gru_layer<<<128, 256, 0, stream>>>(xp, decOut, Whh_d1, bhh_d1, enOut + 255 * H_,
                                       (long)(256 * H_), flags + 12288);

  // ---------------- attention ----------------
  k_gemm_nt<<<dim3(S_ / 128, T_ / 128, B_), 256, 0, stream>>>(
      decOut, H_, nullptr, 0, H_, enOut, H_, nullptr, scT, S_, H_,
      (long)T_ * H_, (long)S_ * H_, (long)T_ * S_);
  k_softmax<<<B_ * T_, 256, 0, stream>>>(scT);
  k_transpose<<<dim3(16, 8, B_), tb, 0, stream>>>(enOut, enOutT, 256, 512);
  k_gemm_nt<<<dim3(H_ / 128, T_ / 128, B_), 256, 0, stream>>>(
      scT, S_, nullptr, 0, S_, enOutT, S_, nullptr, ctx, H_, S_,
      (long)T_ * S_, (long)H_ * S_, (long)T_ * H_);

  // ---------------- final FC ----------------
  k_gemm_mfma_nt<<<dim3(V_ / 128, (B_ * T_) / 128, 1), 256, 0, stream>>>(
      decOut, H_, ctx, H_, H_, fcW, E_, fcb, out, V_, E_);
}

// Round 10
// 4598.614 us; speedup vs baseline: 1.5116x; 1.5116x over previous
//
#include <hip/hip_runtime.h>
#include <math.h>

#define B_ 16
#define S_ 256
#define T_ 256
#define E_ 1024
#define H_ 512
#define G_ 1536
#define V_ 32000

typedef unsigned short u16;
typedef short short8 __attribute__((ext_vector_type(8)));
typedef float f32x4 __attribute__((ext_vector_type(4)));

__device__ inline u16 f2bf(float x) {
  union { float f; unsigned u; } a; a.f = x;
  unsigned r = a.u + 0x7fff + ((a.u >> 16) & 1);
  return (u16)(r >> 16);
}
__device__ inline float bf2f(u16 h) {
  union { unsigned u; float f; } a; a.u = ((unsigned)h) << 16;
  return a.f;
}

// Coherent (MALL-level) 16B load: bypasses L1+L2, no cache maintenance.
// Caller MUST execute s_waitcnt vmcnt(0) before using the result.
__device__ inline f32x4 load_f4_coh(const float* p) {
  f32x4 v;
  asm volatile("global_load_dwordx4 %0, %1, off sc0 sc1" : "=v"(v) : "v"(p));
  return v;
}

__device__ inline float dot4(f32x4 a, f32x4 b) {
  return a.x * b.x + a.y * b.y + a.z * b.z + a.w * b.w;
}

// ---------------- embedding gathers ----------------
__global__ __launch_bounds__(256) void k_embed_enc(const int* __restrict__ sen,
                                                   const float* __restrict__ emb,
                                                   float* __restrict__ out) {
  long row = blockIdx.x;
  int tid = threadIdx.x;
  long e = sen[row];
  float4 v = *(const float4*)(emb + e * E_ + tid * 4);
  *(float4*)(out + row * E_ + tid * 4) = v;
}

__global__ __launch_bounds__(256) void k_embed_dec(const int* __restrict__ zh,
                                                   const float* __restrict__ emb,
                                                   float* __restrict__ out) {
  long row = blockIdx.x;
  int b = (int)(row >> 8), t = (int)(row & 255);
  int tid = threadIdx.x;
  long e = (t == 0) ? (V_ - 2) : zh[b * T_ + t - 1];
  float4 v = *(const float4*)(emb + e * E_ + tid * 4);
  *(float4*)(out + row * E_ + tid * 4) = v;
}

// ---------------- batched 32x32 tiled transpose ----------------
__global__ __launch_bounds__(256) void k_transpose(const float* __restrict__ in,
                                                   float* __restrict__ out, int R, int C) {
  __shared__ float tile[32][33];
  long z = blockIdx.z;
  const float* inz = in + z * (long)R * C;
  float* outz = out + z * (long)R * C;
  int x = blockIdx.x * 32 + threadIdx.x;
  int y0 = blockIdx.y * 32;
#pragma unroll
  for (int i = threadIdx.y; i < 32; i += 8)
    tile[i][threadIdx.x] = inz[(long)(y0 + i) * C + x];
  __syncthreads();
  int xo = y0 + threadIdx.x;
#pragma unroll
  for (int i = threadIdx.y; i < 32; i += 8) {
    int yo = blockIdx.x * 32 + i;
    outz[(long)yo * R + xo] = tile[threadIdx.x][i];
  }
}

// ---------------- fp32 SGEMM (small attention GEMMs) ----------------
__global__ __launch_bounds__(256) void k_gemm_nt(
    const float* __restrict__ A, int lda, const float* __restrict__ A2, int lda2, int kSplit,
    const float* __restrict__ Bm, int ldb, const float* __restrict__ bias,
    float* __restrict__ C, int ldc, int K, long sA, long sB, long sC) {
  __shared__ float As[8][132];
  __shared__ float Bs[8][132];
  int z = blockIdx.z;
  A += z * sA;
  Bm += z * sB;
  C += z * sC;
  int tid = threadIdx.x;
  int bm = blockIdx.y * 128, bn = blockIdx.x * 128;
  int tx = tid & 15, ty = tid >> 4;
  int lr = tid >> 1, lc = (tid & 1) * 4;
  float acc[8][8] = {};
  for (int k0 = 0; k0 < K; k0 += 8) {
    int ka = k0 + lc;
    const float* ap;
    if (A2 != nullptr && ka >= kSplit)
      ap = A2 + (long)(bm + lr) * lda2 + (ka - kSplit);
    else
      ap = A + (long)(bm + lr) * lda + ka;
    float4 a4 = *(const float4*)ap;
    float4 b4 = *(const float4*)(Bm + (long)(bn + lr) * ldb + k0 + lc);
    As[lc + 0][lr] = a4.x; As[lc + 1][lr] = a4.y; As[lc + 2][lr] = a4.z; As[lc + 3][lr] = a4.w;
    Bs[lc + 0][lr] = b4.x; Bs[lc + 1][lr] = b4.y; Bs[lc + 2][lr] = b4.z; Bs[lc + 3][lr] = b4.w;
    __syncthreads();
#pragma unroll
    for (int kk = 0; kk < 8; kk++) {
      float ar[8], br[8];
      *(float4*)&ar[0] = *(const float4*)&As[kk][ty * 8];
      *(float4*)&ar[4] = *(const float4*)&As[kk][ty * 8 + 4];
      *(float4*)&br[0] = *(const float4*)&Bs[kk][tx * 8];
      *(float4*)&br[4] = *(const float4*)&Bs[kk][tx * 8 + 4];
#pragma unroll
      for (int i = 0; i < 8; i++)
#pragma unroll
        for (int j = 0; j < 8; j++) acc[i][j] += ar[i] * br[j];
    }
    __syncthreads();
  }
  float bv[8];
#pragma unroll
  for (int j = 0; j < 8; j++) bv[j] = bias ? bias[bn + tx * 8 + j] : 0.f;
#pragma unroll
  for (int i = 0; i < 8; i++) {
    float* cp = C + (long)(bm + ty * 8 + i) * ldc + bn + tx * 8;
    float4 o0, o1;
    o0.x = acc[i][0] + bv[0]; o0.y = acc[i][1] + bv[1];
    o0.z = acc[i][2] + bv[2]; o0.w = acc[i][3] + bv[3];
    o1.x = acc[i][4] + bv[4]; o1.y = acc[i][5] + bv[5];
    o1.z = acc[i][6] + bv[6]; o1.w = acc[i][7] + bv[7];
    *(float4*)cp = o0;
    *(float4*)(cp + 4) = o1;
  }
}

// ---------------- split-bf16 MFMA GEMM (fp32 in/out) ----------------
__global__ __launch_bounds__(256) void k_gemm_mfma_nt(
    const float* __restrict__ A, int lda, const float* __restrict__ A2, int lda2, int kSplit,
    const float* __restrict__ Bm, int ldb, const float* __restrict__ bias,
    float* __restrict__ C, int ldc, int K) {
  __shared__ u16 Ah[128][40];
  __shared__ u16 Al[128][40];
  __shared__ u16 Bh[128][40];
  __shared__ u16 Bl[128][40];
  int tid = threadIdx.x;
  int bm = blockIdx.y * 128, bn = blockIdx.x * 128;
  int wave = tid >> 6, lane = tid & 63;
  int wm = (wave >> 1) * 64, wn = (wave & 1) * 64;
  int srow = tid >> 1, scol = (tid & 1) * 16;
  int fr = lane & 15, fk = (lane >> 4) * 8, fq = lane >> 4;

  f32x4 acc[4][4] = {};

  for (int k0 = 0; k0 < K; k0 += 32) {
    {
      int ka = k0 + scol;
      const float* ap;
      if (A2 != nullptr && ka >= kSplit)
        ap = A2 + (long)(bm + srow) * lda2 + (ka - kSplit);
      else
        ap = A + (long)(bm + srow) * lda + ka;
      float va[16];
      *(float4*)&va[0] = *(const float4*)ap;
      *(float4*)&va[4] = *(const float4*)(ap + 4);
      *(float4*)&va[8] = *(const float4*)(ap + 8);
      *(float4*)&va[12] = *(const float4*)(ap + 12);
      u16 h[16], l[16];
#pragma unroll
      for (int i = 0; i < 16; i++) {
        u16 hh = f2bf(va[i]);
        h[i] = hh;
        l[i] = f2bf(va[i] - bf2f(hh));
      }
      *(short8*)&Ah[srow][scol] = *(short8*)&h[0];
      *(short8*)&Ah[srow][scol + 8] = *(short8*)&h[8];
      *(short8*)&Al[srow][scol] = *(short8*)&l[0];
      *(short8*)&Al[srow][scol + 8] = *(short8*)&l[8];
    }
    {
      const float* bp = Bm + (long)(bn + srow) * ldb + k0 + scol;
      float vb[16];
      *(float4*)&vb[0] = *(const float4*)bp;
      *(float4*)&vb[4] = *(const float4*)(bp + 4);
      *(float4*)&vb[8] = *(const float4*)(bp + 8);
      *(float4*)&vb[12] = *(const float4*)(bp + 12);
      u16 h[16], l[16];
#pragma unroll
      for (int i = 0; i < 16; i++) {
        u16 hh = f2bf(vb[i]);
        h[i] = hh;
        l[i] = f2bf(vb[i] - bf2f(hh));
      }
      *(short8*)&Bh[srow][scol] = *(short8*)&h[0];
      *(short8*)&Bh[srow][scol + 8] = *(short8*)&h[8];
      *(short8*)&Bl[srow][scol] = *(short8*)&l[0];
      *(short8*)&Bl[srow][scol + 8] = *(short8*)&l[8];
    }
    __syncthreads();
    short8 afh[4], afl[4];
#pragma unroll
    for (int mt = 0; mt < 4; mt++) {
      afh[mt] = *(const short8*)&Ah[wm + mt * 16 + fr][fk];
      afl[mt] = *(const short8*)&Al[wm + mt * 16 + fr][fk];
    }
#pragma unroll
    for (int nt = 0; nt < 4; nt++) {
      short8 bh = *(const short8*)&Bh[wn + nt * 16 + fr][fk];
      short8 bl = *(const short8*)&Bl[wn + nt * 16 + fr][fk];
#pragma unroll
      for (int mt = 0; mt < 4; mt++) {
        acc[mt][nt] = __builtin_amdgcn_mfma_f32_16x16x32_bf16(afh[mt], bh, acc[mt][nt], 0, 0, 0);
        acc[mt][nt] = __builtin_amdgcn_mfma_f32_16x16x32_bf16(afh[mt], bl, acc[mt][nt], 0, 0, 0);
        acc[mt][nt] = __builtin_amdgcn_mfma_f32_16x16x32_bf16(afl[mt], bh, acc[mt][nt], 0, 0, 0);
      }
    }
    __syncthreads();
  }
#pragma unroll
  for (int nt = 0; nt < 4; nt++) {
    int col = bn + wn + nt * 16 + fr;
    float bv = bias ? bias[col] : 0.f;
#pragma unroll
    for (int mt = 0; mt < 4; mt++) {
      int row = bm + wm + mt * 16 + fq * 4;
#pragma unroll
      for (int j = 0; j < 4; j++)
        C[(long)(row + j) * ldc + col] = acc[mt][nt][j] + bv;
    }
  }
}

// ---------------- batch-partitioned persistent GRU layer ----------------
// KEY: the GRU recurrence is independent per batch sample. grid = 256 blocks:
// bid = b*16 + js. Block owns batch b, j in [js*32, js*32+32). Sync is only
// within the 16 blocks of batch b: poll 16 epoch slots, restage 2KB of h,
// publish 32 floats (one 128B window in y).
// Thread: wave = tid>>6, lane = jsub*32 + ksl. Thread's j's: jbase+e (4),
// k-slice: ksl*16..+15. Weights: 48 f32x4 in VGPRs, loaded once.
// hls layout (v4-proven interleave): pos(k) = ((k>>2)&3)*132 + (k>>4)*4 + (k&3).
// Sync = rounds 5-7 proven: relaxed sc0sc1 stores, vmcnt(0)-ack + barrier,
// relaxed epoch store; no RMW, no cache maintenance. LDS 2.1KB -> trivially
// co-resident; batch groups independent -> no global co-residency requirement.
#define WSLOT 32
__global__ __launch_bounds__(256) void k_gru_b(
    const float* __restrict__ xp, float* __restrict__ y,
    const float* __restrict__ Whh, const float* __restrict__ bhh,
    const float* __restrict__ hinit, long hbs, int* __restrict__ ep) {
  __shared__ float hls[536];
  int tid = threadIdx.x;
  int wave = tid >> 6, lane = tid & 63;
  int jsub = lane >> 5, ksl = lane & 31;
  int b = blockIdx.x >> 4, js = blockIdx.x & 15;
  int jbase = js * 32 + wave * 8 + jsub * 4;

  // ---- weights (4 j x 3 gates x 16 k) + biases into registers, once ----
  f32x4 w[4][3][4];
  float bb[4][3];
#pragma unroll
  for (int e = 0; e < 4; e++)
#pragma unroll
    for (int g = 0; g < 3; g++) {
      const float* r = Whh + (long)(g * 512 + jbase + e) * 512 + ksl * 16;
#pragma unroll
      for (int q = 0; q < 4; q++) w[e][g][q] = *(const f32x4*)(r + q * 4);
      bb[e][g] = bhh[g * 512 + jbase + e];
    }
  bool gl = (ksl < 4);
  int jme = jbase + ksl;  // gate lane's output j (e = ksl)
  const int* epb = ep + (long)(b * 16 + (lane & 15)) * WSLOT;
  int* epMine = ep + (long)(b * 16 + js) * WSLOT;
  float* yb = y + (long)b * (256 * 512);
  const float* xpb = xp + (long)b * (256 * 1536);

  for (int t = 0; t < 256; t++) {
    // ---- xp prefetch for gate lanes (independent of recurrence) ----
    float xr = 0.f, xz = 0.f, xn = 0.f;
    if (gl) {
      const float* xpt = xpb + (long)t * 1536 + jme;
      xr = xpt[0]; xz = xpt[512]; xn = xpt[1024];
    }
    // ---- wait for the 15 peers of batch b: ep >= t ----
    if (t > 0) {
      if (wave == 0) {
        while (true) {
          int e0;
          asm volatile("global_load_dword %0, %1, off sc0 sc1" : "=v"(e0) : "v"(epb));
          asm volatile("s_waitcnt vmcnt(0)" ::: "memory");
          if (__ballot(e0 >= t) == ~0ull) break;
          __builtin_amdgcn_s_sleep(1);
        }
      }
      __syncthreads();
    }
    // ---- stage h(t-1)[b][0..511] (2KB) via coherent 16B loads ----
    if (tid < 128) {
      const float* src = (t == 0) ? (hinit + (long)b * hbs + tid * 4)
                                  : (yb + (long)(t - 1) * 512 + tid * 4);
      f32x4 v = load_f4_coh(src);
      asm volatile("s_waitcnt vmcnt(0)" ::: "memory");
      __builtin_amdgcn_sched_barrier(0);
      *(f32x4*)&hls[(tid & 3) * 132 + (tid >> 2) * 4] = v;
    }
    __syncthreads();
    // ---- matvec: 4 j x 3 gates over own 16 k, weights in regs ----
    f32x4 h0 = *(const f32x4*)&hls[ksl * 4];
    f32x4 h1 = *(const f32x4*)&hls[132 + ksl * 4];
    f32x4 h2 = *(const f32x4*)&hls[264 + ksl * 4];
    f32x4 h3 = *(const f32x4*)&hls[396 + ksl * 4];
    float a[4][3];
#pragma unroll
    for (int e = 0; e < 4; e++)
#pragma unroll
      for (int g = 0; g < 3; g++)
        a[e][g] = dot4(h0, w[e][g][0]) + dot4(h1, w[e][g][1]) +
                  dot4(h2, w[e][g][2]) + dot4(h3, w[e][g][3]);
    // ---- butterfly reduce over 32 ksl lanes (masks 1..16 keep jsub) ----
#pragma unroll
    for (int m = 1; m <= 16; m <<= 1)
#pragma unroll
      for (int e = 0; e < 4; e++) {
        a[e][0] += __shfl_xor(a[e][0], m);
        a[e][1] += __shfl_xor(a[e][1], m);
        a[e][2] += __shfl_xor(a[e][2], m);
      }
    // ---- gates (lanes ksl<4, e = ksl; static-index select) ----
    if (gl) {
      float hr = 0.f, hz = 0.f, hn = 0.f, Br = 0.f, Bz = 0.f, Bn = 0.f;
#pragma unroll
      for (int e = 0; e < 4; e++)
        if (ksl == e) {
          hr = a[e][0]; hz = a[e][1]; hn = a[e][2];
          Br = bb[e][0]; Bz = bb[e][1]; Bn = bb[e][2];
        }
      float r = 1.f / (1.f + __expf(-(xr + hr + Br)));
      float z = 1.f / (1.f + __expf(-(xz + hz + Bz)));
      float n = tanhf(xn + r * (hn + Bn));
      float hp = hls[((jme >> 2) & 3) * 132 + (jme >> 4) * 4 + (jme & 3)];
      float hv = (1.f - z) * n + z * hp;
      __hip_atomic_store(&yb[(long)t * 512 + jme], hv,
                         __ATOMIC_RELAXED, __HIP_MEMORY_SCOPE_AGENT);
    }
    // ---- publish: own stores acked at MALL, then epoch ----
    asm volatile("s_waitcnt vmcnt(0)" ::: "memory");
    __syncthreads();
    if (tid == 0)
      __hip_atomic_store(epMine, t + 1, __ATOMIC_RELAXED, __HIP_MEMORY_SCOPE_AGENT);
  }
}

// ---------------- row softmax over 256 ----------------
__global__ __launch_bounds__(256) void k_softmax(float* __restrict__ p) {
  long row = blockIdx.x;
  int tid = threadIdx.x;
  float* pr = p + row * 256;
  float v = pr[tid];
  float m = v;
#pragma unroll
  for (int off = 32; off >= 1; off >>= 1) m = fmaxf(m, __shfl_xor(m, off));
  __shared__ float wmax[4];
  __shared__ float wsum[4];
  int wv = tid >> 6, ln = tid & 63;
  if (ln == 0) wmax[wv] = m;
  __syncthreads();
  m = fmaxf(fmaxf(wmax[0], wmax[1]), fmaxf(wmax[2], wmax[3]));
  float e = expf(v - m);
  float s = e;
#pragma unroll
  for (int off = 32; off >= 1; off >>= 1) s += __shfl_xor(s, off);
  if (ln == 0) wsum[wv] = s;
  __syncthreads();
  s = wsum[0] + wsum[1] + wsum[2] + wsum[3];
  pr[tid] = e / s;
}

extern "C" void kernel_launch(void* const* d_in, const int* in_sizes, int n_in,
                              void* d_out, int out_size, void* d_ws, size_t ws_size,
                              hipStream_t stream) {
  const int* en_sen = (const int*)d_in[0];
  const int* zh_sen = (const int*)d_in[1];
  const float* en_emb = (const float*)d_in[2];
  const float* zh_emb = (const float*)d_in[3];
  const float* h0 = (const float*)d_in[4];
  const float* Wih_e0 = (const float*)d_in[5];
  const float* Whh_e0 = (const float*)d_in[6];
  const float* bih_e0 = (const float*)d_in[7];
  const float* bhh_e0 = (const float*)d_in[8];
  const float* Wih_e1 = (const float*)d_in[9];
  const float* Whh_e1 = (const float*)d_in[10];
  const float* bih_e1 = (const float*)d_in[11];
  const float* bhh_e1 = (const float*)d_in[12];
  const float* Wih_d0 = (const float*)d_in[13];
  const float* Whh_d0 = (const float*)d_in[14];
  const float* bih_d0 = (const float*)d_in[15];
  const float* bhh_d0 = (const float*)d_in[16];
  const float* Wih_d1 = (const float*)d_in[17];
  const float* Whh_d1 = (const float*)d_in[18];
  const float* bih_d1 = (const float*)d_in[19];
  const float* bhh_d1 = (const float*)d_in[20];
  const float* fcW = (const float*)d_in[21];
  const float* fcb = (const float*)d_in[22];
  float* out = (float*)d_out;

  // FC inputs must not alias d_out -> d_ws (16 MiB, validated R2-R7).
  float* decOut = (float*)d_ws;
  float* ctx = decOut + 2097152;

  // d_out scratch: epoch slots [4 layers][256 blocks][32 ints] = 128 KB, then buffers.
  int* flags = (int*)d_out;              // 32768 ints
  float* bufE = (float*)d_out + 32768;   // ex / zx  [B*256*1024]
  float* xp = bufE + 4194304;            // [B*256*1536]
  float* bufY = xp + 6291456;            // y_e0 then y_d0
  float* enOut = bufY + 2097152;         // y_e1
  float* scT = enOut + 2097152;          // scores/attn [B,T,S]
  float* enOutT = scT + 1048576;         // [B,512,256]

  hipMemsetAsync(flags, 0, 32768 * sizeof(int), stream);

  dim3 tb(32, 8);

  // ---------------- encoder ----------------
  k_embed_enc<<<B_ * S_, 256, 0, stream>>>(en_sen, en_emb, bufE);
  k_gemm_mfma_nt<<<dim3(G_ / 128, (B_ * S_) / 128, 1), 256, 0, stream>>>(
      bufE, E_, nullptr, 0, E_, Wih_e0, E_, bih_e0, xp, G_, E_);
  k_gru_b<<<256, 256, 0, stream>>>(xp, bufY, Whh_e0, bhh_e0, h0, (long)H_, flags);
  k_gemm_mfma_nt<<<dim3(G_ / 128, (B_ * S_) / 128, 1), 256, 0, stream>>>(
      bufY, H_, nullptr, 0, H_, Wih_e1, H_, bih_e1, xp, G_, H_);
  k_gru_b<<<256, 256, 0, stream>>>(xp, enOut, Whh_e1, bhh_e1, h0 + B_ * H_, (long)H_,
                                   flags + 8192);

  // ---------------- decoder ----------------
  k_embed_dec<<<B_ * T_, 256, 0, stream>>>(zh_sen, zh_emb, bufE);
  k_gemm_mfma_nt<<<dim3(G_ / 128, (B_ * T_) / 128, 1), 256, 0, stream>>>(
      bufE, E_, nullptr, 0, E_, Wih_d0, E_, bih_d0, xp, G_, E_);
  // init h = y_e0[:,255,:] in bufY; row 255 only read at t=0, overwritten at t=255
  k_gru_b<<<256, 256, 0, stream>>>(xp, bufY, Whh_d0, bhh_d0, bufY + 255 * H_,
                                   (long)(256 * H_), flags + 16384);
  k_gemm_mfma_nt<<<dim3(G_ / 128, (B_ * T_) / 128, 1), 256, 0, stream>>>(
      bufY, H_, nullptr, 0, H_, Wih_d1, H_, bih_d1, xp, G_, H_);
  k_gru_b<<<256, 256, 0, stream>>>(xp, decOut, Whh_d1, bhh_d1, enOut + 255 * H_,
                                   (long)(256 * H_), flags + 24576);

  // ---------------- attention ----------------
  k_gemm_nt<<<dim3(S_ / 128, T_ / 128, B_), 256, 0, stream>>>(
      decOut, H_, nullptr, 0, H_, enOut, H_, nullptr, scT, S_, H_,
      (long)T_ * H_, (long)S_ * H_, (long)T_ * S_);
  k_softmax<<<B_ * T_, 256, 0, stream>>>(scT);
  k_transpose<<<dim3(16, 8, B_), tb, 0, stream>>>(enOut, enOutT, 256, 512);
  k_gemm_nt<<<dim3(H_ / 128, T_ / 128, B_), 256, 0, stream>>>(
      scT, S_, nullptr, 0, S_, enOutT, S_, nullptr, ctx, H_, S_,
      (long)T_ * S_, (long)H_ * S_, (long)T_ * H_);

  // ---------------- final FC ----------------
  k_gemm_mfma_nt<<<dim3(V_ / 128, (B_ * T_) / 128, 1), 256, 0, stream>>>(
      decOut, H_, ctx, H_, H_, fcW, E_, fcb, out, V_, E_);
}